// Round 5
// baseline (16121.013 us; speedup 1.0000x reference)
//
#include <hip/hip_runtime.h>
#include <math.h>

// Problem constants
#define NB 1024      // batch
#define NH 512       // hidden
#define NT 256       // time steps
#define NCD 2        // per-step output dims

typedef unsigned short u16;
typedef __bf16 bf16x8 __attribute__((ext_vector_type(8)));
typedef float  f32x4  __attribute__((ext_vector_type(4)));

#define MFMA_BF16 __builtin_amdgcn_mfma_f32_16x16x32_bf16

__device__ __forceinline__ float sigf(float x) { return 1.0f / (1.0f + expf(-x)); }
__device__ __forceinline__ float b2f(u16 u) {
    union { unsigned i; float f; } v; v.i = ((unsigned)u) << 16; return v.f;
}
__device__ __forceinline__ u16 f2b(float f) {   // RTNE
    union { float f; unsigned i; } v; v.f = f;
    unsigned r = v.i + 0x7fffu + ((v.i >> 16) & 1u);
    return (u16)(r >> 16);
}

// async 16B global -> LDS (direct-to-shared DMA); lane L lands at base+L*16.
__device__ __forceinline__ void async_cp16(const void* gptr, void* lptr) {
    __builtin_amdgcn_global_load_lds(
        (const __attribute__((address_space(1))) unsigned int*)gptr,
        (__attribute__((address_space(3))) unsigned int*)lptr,
        16, 0, 0);
}

// ---------------------------------------------------------------------------
// 16-block group barrier (monotonic generation). Agent-scope atomics:
// arrivals release their stores; exit does one acquire fence. Thread 0 only;
// surrounding __syncthreads cover the block.
// ---------------------------------------------------------------------------
__device__ __forceinline__ void group_barrier(unsigned* cnt, unsigned* gen,
                                              unsigned nb, int tid) {
    __syncthreads();
    if (tid == 0) {
        const unsigned g0 =
            __hip_atomic_load(gen, __ATOMIC_RELAXED, __HIP_MEMORY_SCOPE_AGENT);
        const unsigned arr =
            __hip_atomic_fetch_add(cnt, 1u, __ATOMIC_ACQ_REL, __HIP_MEMORY_SCOPE_AGENT);
        if (arr == nb - 1) {
            __hip_atomic_store(cnt, 0u, __ATOMIC_RELAXED, __HIP_MEMORY_SCOPE_AGENT);
            __hip_atomic_fetch_add(gen, 1u, __ATOMIC_RELEASE, __HIP_MEMORY_SCOPE_AGENT);
        } else {
            while (__hip_atomic_load(gen, __ATOMIC_RELAXED,
                                     __HIP_MEMORY_SCOPE_AGENT) == g0)
                __builtin_amdgcn_s_sleep(1);
            __builtin_amdgcn_fence(__ATOMIC_ACQUIRE, "agent");
        }
    }
    __syncthreads();
}

// ---------------------------------------------------------------------------
// weight conversion fp32 -> bf16 (three 2048x512 LSTM weights)
// ---------------------------------------------------------------------------
__global__ __launch_bounds__(256) void convert3(
    const float* __restrict__ a, const float* __restrict__ b,
    const float* __restrict__ c,
    u16* __restrict__ oa, u16* __restrict__ ob, u16* __restrict__ oc)
{
    const int i = blockIdx.x * 256 + threadIdx.x;   // < 2048*512
    oa[i] = f2b(a[i]); ob[i] = f2b(b[i]); oc[i] = f2b(c[i]);
}

__global__ __launch_bounds__(256) void bsum_k(
    const float* __restrict__ bi1, const float* __restrict__ bh1,
    const float* __restrict__ bi2, const float* __restrict__ bh2,
    float* __restrict__ o1, float* __restrict__ o2)
{
    const int i = blockIdx.x * 256 + threadIdx.x;   // < 2048
    o1[i] = bi1[i] + bh1[i];
    o2[i] = bi2[i] + bh2[i];
}

// One-time transpose of Wo1 (256x512) -> Wo1T (512x256), fp32  [R2-verified]
__global__ __launch_bounds__(256) void transpose_wo1(
    const float* __restrict__ Wo1, float* __restrict__ Wo1T)
{
    const int idx = blockIdx.x * 256 + threadIdx.x;  // < 256*512
    const int r = idx >> 9, k = idx & 511;
    Wo1T[k * 256 + r] = Wo1[idx];
}

// ---------------------------------------------------------------------------
// init: [h0 | c0] = z @ W_proj^T + b_proj ; h0 (bf16) -> h1,h2 ; c0 (f32)
// ---------------------------------------------------------------------------
__global__ __launch_bounds__(256) void init_kernel(
    const float* __restrict__ zp, const float* __restrict__ zs,
    const float* __restrict__ zst, const float* __restrict__ Wp,
    const float* __restrict__ bp,
    u16* __restrict__ h1, float* __restrict__ c1,
    u16* __restrict__ h2, float* __restrict__ c2)
{
    __shared__ float z[4][256];
    const int tid = threadIdx.x;
    const int b0  = blockIdx.x * 4;
    for (int i = tid; i < 4 * 256; i += 256) {
        const int bb = i >> 8, k = i & 255;
        float v;
        if (k < 64)       v = zp [(b0 + bb) * 64  + k];
        else if (k < 128) v = zs [(b0 + bb) * 64  + (k - 64)];
        else              v = zst[(b0 + bb) * 128 + (k - 128)];
        z[bb][k] = v;
    }
    __syncthreads();
    for (int rt = 0; rt < 4; ++rt) {
        const int r = rt * 256 + tid;          // 0..1023
        const float bias = bp[r];
        float a0 = bias, a1 = bias, a2 = bias, a3 = bias;
        for (int k = 0; k < 256; ++k) {
            const float w = Wp[r * 256 + k];
            a0 += z[0][k] * w; a1 += z[1][k] * w;
            a2 += z[2][k] * w; a3 += z[3][k] * w;
        }
        const float acc[4] = {a0, a1, a2, a3};
        for (int bb = 0; bb < 4; ++bb) {
            const int b = b0 + bb;
            if (r < NH) {
                h1[b * NH + r] = f2b(acc[bb]);
                h2[b * NH + r] = f2b(acc[bb]);
            } else {
                c1[b * NH + r - NH] = acc[bb];
                c2[b * NH + r - NH] = acc[bb];
            }
        }
    }
}

// ---------------------------------------------------------------------------
// LSTM phase (R4-verified body, now a device function).
// ---------------------------------------------------------------------------
__device__ __forceinline__ void lstm_phase(
    char* smem,
    const u16* __restrict__ A0, const u16* __restrict__ W0,
    const u16* __restrict__ A1, const u16* __restrict__ W1,
    const float* __restrict__ bsum,
    const float* __restrict__ xin, const float* __restrict__ Wx,
    float* __restrict__ c, u16* __restrict__ hnext,
    const int npass,
    const int tid, const int lane, const int wv, const int g, const int mh,
    const int l15, const int q, const int u0, const int b0,
    const int* goff, const int* isa)
{
    float* eg = (float*)smem;

    f32x4 acc[2][2];
#pragma unroll
    for (int mi = 0; mi < 2; ++mi)
#pragma unroll
        for (int ni = 0; ni < 2; ++ni)
            acc[mi][ni] = (f32x4){0.f, 0.f, 0.f, 0.f};

    const int M = npass * 8;            // total macro-tiles

    auto issue = [&](int m) {
        const u16* __restrict__ Ap = (m < 8) ? A0 : A1;
        const u16* __restrict__ Wp = (m < 8) ? W0 : W1;
        const int k0 = (m & 7) * 64;
        char* base = smem + (m & 1) * 24576;
#pragma unroll
        for (int i = 0; i < 3; ++i) {
            const u16* gp = (isa[i] ? Ap : Wp) + (goff[i] + k0);
            async_cp16((const void*)gp, (void*)(base + ((wv * 3 + i) << 10)));
        }
    };

    issue(0);
    for (int m = 0; m < M; ++m) {
        __syncthreads();                 // drains vmcnt: loads(m) complete
        if (m + 1 < M) issue(m + 1);     // prefetch into other buffer
        const char* bA = smem + (m & 1) * 24576;
        const char* bW = bA + 8192;
#pragma unroll
        for (int khi = 0; khi < 2; ++khi) {
            bf16x8 bfr[2];
#pragma unroll
            for (int ni = 0; ni < 2; ++ni) {
                const int wrow = g * 32 + ni * 16 + l15;
                const int j = (khi * 4 + q) ^ (wrow & 7);
                bfr[ni] = *(const bf16x8*)(bW + wrow * 128 + j * 16);
            }
#pragma unroll
            for (int mi = 0; mi < 2; ++mi) {
                const int row = mh * 32 + mi * 16 + l15;
                const int j = (khi * 4 + q) ^ (row & 7);
                const bf16x8 av = *(const bf16x8*)(bA + row * 128 + j * 16);
                acc[mi][0] = MFMA_BF16(av, bfr[0], acc[mi][0], 0, 0, 0);
                acc[mi][1] = MFMA_BF16(av, bfr[1], acc[mi][1], 0, 0, 0);
            }
        }
    }

    __syncthreads();
    // dump gate pre-activations: eg[g][b_local][u_local], stride 33
    // C/D layout: row(batch) = q*4+r, col(unit) = l15   [m89-verified]
#pragma unroll
    for (int mi = 0; mi < 2; ++mi)
#pragma unroll
        for (int ni = 0; ni < 2; ++ni)
#pragma unroll
            for (int r = 0; r < 4; ++r)
                eg[(g * 64 + mh * 32 + mi * 16 + q * 4 + r) * 33 + ni * 16 + l15]
                    = acc[mi][ni][r];
    __syncthreads();

    // fused pointwise cell update: thread -> unit u, 4 batch rows
    const int u  = tid & 31;
    const int bg = tid >> 5;            // 0..15
    const int ug = u0 + u;
    float bs[4], wx0[4], wx1[4];
#pragma unroll
    for (int g4 = 0; g4 < 4; ++g4) bs[g4] = bsum[g4 * NH + ug];
    if (Wx) {
#pragma unroll
        for (int g4 = 0; g4 < 4; ++g4) {
            wx0[g4] = Wx[(g4 * NH + ug) * 2 + 0];
            wx1[g4] = Wx[(g4 * NH + ug) * 2 + 1];
        }
    }
#pragma unroll
    for (int jj = 0; jj < 4; ++jj) {
        const int bl = bg * 4 + jj;
        const int b  = b0 + bl;
        float gv[4];
#pragma unroll
        for (int g4 = 0; g4 < 4; ++g4) gv[g4] = eg[(g4 * 64 + bl) * 33 + u] + bs[g4];
        if (Wx) {
            const float x0 = xin[b * 2], x1 = xin[b * 2 + 1];
#pragma unroll
            for (int g4 = 0; g4 < 4; ++g4) gv[g4] += x0 * wx0[g4] + x1 * wx1[g4];
        }
        const float iv = sigf(gv[0]);
        const float fv = sigf(gv[1]);
        const float gg = tanhf(gv[2]);
        const float ov = sigf(gv[3]);
        const size_t idx = (size_t)b * NH + ug;
        const float cn = fv * c[idx] + iv * gg;
        c[idx] = cn;
        hnext[idx] = f2b(ov * tanhf(cn));
    }
}

// ---------------------------------------------------------------------------
// Out phase (R2-verified fp32 math, remapped to 512 threads, 4 batch rows).
// thread t: neuron n = t&255, row-pair hh = t>>8.
// ---------------------------------------------------------------------------
__device__ __forceinline__ void out_phase(
    char* smem, const u16* __restrict__ h2, const float* __restrict__ Wo1T,
    const float* __restrict__ bo1, const float* __restrict__ Wo2,
    const float* __restrict__ bo2, float* __restrict__ xbuf,
    float* __restrict__ outp, const int t, const int tid, const int r0)
{
    float* hsh = (float*)smem;            // [4][512] fp32 = 8 KB
    float* red = (float*)(smem + 8192);   // [8 waves][4] = 128 B
    for (int i = tid; i < 4 * NH; i += 512)
        hsh[i] = b2f(h2[(size_t)(r0 + (i >> 9)) * NH + (i & 511)]);
    __syncthreads();

    const int n  = tid & 255;
    const int hh = tid >> 8;              // 0..1 -> rows hh*2, hh*2+1
    const float* hr0 = hsh + (hh * 2) * NH;
    const float* hr1 = hr0 + NH;
    float a0 = 0.f, a1 = 0.f;
    for (int k = 0; k < NH; ++k) {
        const float w = Wo1T[k * 256 + n];   // lanes n-consecutive: coalesced
        a0 += hr0[k] * w;
        a1 += hr1[k] * w;
    }
    const float bn = bo1[n], w20 = Wo2[n], w21 = Wo2[256 + n];
    const float s0 = fmaxf(a0 + bn, 0.f), s1 = fmaxf(a1 + bn, 0.f);
    float p[4] = { s0 * w20, s0 * w21, s1 * w20, s1 * w21 };
#pragma unroll
    for (int off = 32; off > 0; off >>= 1)
#pragma unroll
        for (int r = 0; r < 4; ++r) p[r] += __shfl_down(p[r], off, 64);
    if ((tid & 63) == 0)
#pragma unroll
        for (int r = 0; r < 4; ++r) red[(tid >> 6) * 4 + r] = p[r];
    __syncthreads();
    if (tid < 8) {
        const int hh2 = tid >> 2, rp = (tid >> 1) & 1, cc = tid & 1;
        float y = bo2[cc];
#pragma unroll
        for (int wq = 0; wq < 4; ++wq)
            y += red[(hh2 * 4 + wq) * 4 + rp * 2 + cc];
        const int b = r0 + hh2 * 2 + rp;
        xbuf[b * NCD + cc] = y;
        outp[(size_t)b * (NT * NCD) + t * NCD + cc] = y;
    }
}

// ---------------------------------------------------------------------------
// Persistent kernel: whole T-loop in one cooperative launch.
// 256 blocks x 512 threads, 1 block/CU. Block = (grp = batch tile of 64,
// ut = unit tile of 32). Each grp's 16 blocks form an independent pipeline
// synchronized by group_barrier (3 per step).
// ---------------------------------------------------------------------------
__global__ __launch_bounds__(512, 1) void persistent_kernel(
    u16* h1a, u16* h1b, u16* h2a, u16* h2b,
    float* c1, float* c2, float* xb,
    const float* bs1, const float* bs2, const float* Wo1T,
    const u16* Whh1b, const u16* Wih2b, const u16* Whh2b,
    const float* Wih1, const float* Wo2, const float* bo1, const float* bo2,
    float* outp, unsigned* barr)
{
    __shared__ __align__(16) char smem[49152];

    const int tid  = threadIdx.x;
    const int lane = tid & 63;
    const int wv   = tid >> 6;
    const int g    = wv & 3;
    const int mh   = wv >> 2;
    const int l15  = lane & 15;
    const int q    = lane >> 4;
    const int bx   = blockIdx.x;
    const int grp  = bx >> 4;           // batch group 0..15
    const int ut   = bx & 15;           // unit tile 0..15
    const int b0   = grp * 64;
    const int u0   = ut * 32;
    const int r0   = grp * 64 + ut * 4; // out-phase rows
    unsigned* cnt  = barr + grp * 128;
    unsigned* gen  = barr + grp * 128 + 64;

    // staging descriptors (phase-independent): 1536 chunks per macro
    int goff[3], isa[3];
#pragma unroll
    for (int i = 0; i < 3; ++i) {
        const int cidx = (wv * 3 + i) * 64 + lane;   // 0..1535
        if (cidx < 512) {
            const int row = cidx >> 3;
            const int kc  = (cidx & 7) ^ (row & 7);
            goff[i] = (b0 + row) * NH + kc * 8;
            isa[i]  = 1;
        } else {
            const int rc   = cidx - 512;
            const int wrow = rc >> 3;                // g*32+uu
            const int kc   = (rc & 7) ^ (wrow & 7);
            goff[i] = ((wrow >> 5) * NH + u0 + (wrow & 31)) * NH + kc * 8;
            isa[i]  = 0;
        }
    }

    u16 *h1c = h1a, *h1n = h1b, *h2c = h2a, *h2n = h2b;
    for (int t = 0; t < NT; ++t) {
        lstm_phase(smem, h1c, Whh1b, (const u16*)0, (const u16*)0,
                   bs1, xb, Wih1, c1, h1n, 1,
                   tid, lane, wv, g, mh, l15, q, u0, b0, goff, isa);
        group_barrier(cnt, gen, 16, tid);
        lstm_phase(smem, h1n, Wih2b, h2c, Whh2b,
                   bs2, (const float*)0, (const float*)0, c2, h2n, 2,
                   tid, lane, wv, g, mh, l15, q, u0, b0, goff, isa);
        group_barrier(cnt, gen, 16, tid);
        out_phase(smem, h2n, Wo1T, bo1, Wo2, bo2, xb, outp, t, tid, r0);
        group_barrier(cnt, gen, 16, tid);
        u16* tmp = h1c; h1c = h1n; h1n = tmp;
        tmp = h2c; h2c = h2n; h2n = tmp;
    }
}

// ---------------------------------------------------------------------------
extern "C" void kernel_launch(void* const* d_in, const int* in_sizes, int n_in,
                              void* d_out, int out_size, void* d_ws, size_t ws_size,
                              hipStream_t stream)
{
    const float* zp   = (const float*)d_in[0];
    const float* zsk  = (const float*)d_in[1];
    const float* zst  = (const float*)d_in[2];
    const float* Wp   = (const float*)d_in[3];
    const float* bp   = (const float*)d_in[4];
    const float* Wih1 = (const float*)d_in[5];
    const float* Whh1 = (const float*)d_in[6];
    const float* bih1 = (const float*)d_in[7];
    const float* bhh1 = (const float*)d_in[8];
    const float* Wih2 = (const float*)d_in[9];
    const float* Whh2 = (const float*)d_in[10];
    const float* bih2 = (const float*)d_in[11];
    const float* bhh2 = (const float*)d_in[12];
    const float* Wo1  = (const float*)d_in[13];
    const float* bo1  = (const float*)d_in[14];
    const float* Wo2  = (const float*)d_in[15];
    const float* bo2  = (const float*)d_in[16];

    const size_t BH = (size_t)NB * NH;          // 524288
    u16*   h1a   = (u16*)d_ws;
    u16*   h1b   = h1a + BH;
    u16*   h2a   = h1b + BH;
    u16*   h2b   = h2a + BH;
    float* c1    = (float*)(h2b + BH);
    float* c2    = c1 + BH;
    float* xb    = c2 + BH;                     // 2048 used (pad 4096)
    float* bs1   = xb + 4096;                   // 2048
    float* bs2   = bs1 + 2048;                  // 2048
    float* Wo1T  = bs2 + 2048;                  // 131072 floats
    u16*   Whh1b = (u16*)(Wo1T + 131072);       // 1048576 each
    u16*   Wih2b = Whh1b + 1048576;
    u16*   Whh2b = Wih2b + 1048576;
    unsigned* barr = (unsigned*)(Whh2b + 1048576);  // 16 grps x 128 u32 = 8KB
    // total ~14.6 MB of d_ws

    convert3<<<(2048 * 512) / 256, 256, 0, stream>>>(Whh1, Wih2, Whh2, Whh1b, Wih2b, Whh2b);
    transpose_wo1<<<(256 * 512) / 256, 256, 0, stream>>>(Wo1, Wo1T);
    bsum_k<<<2048 / 256, 256, 0, stream>>>(bih1, bhh1, bih2, bhh2, bs1, bs2);
    hipMemsetAsync(xb, 0, NB * NCD * sizeof(float), stream);   // x0 = 0
    hipMemsetAsync(barr, 0, 16 * 128 * sizeof(unsigned), stream);
    init_kernel<<<NB / 4, 256, 0, stream>>>(zp, zsk, zst, Wp, bp, h1a, c1, h2a, c2);

    float* outp = (float*)d_out;
    void* args[] = {
        &h1a, &h1b, &h2a, &h2b, &c1, &c2, &xb, &bs1, &bs2, &Wo1T,
        &Whh1b, &Wih2b, &Whh2b, &Wih1, &Wo2, &bo1, &bo2, &outp, &barr
    };
    hipLaunchCooperativeKernel((void*)persistent_kernel,
                               dim3(256), dim3(512), args, 0, stream);
}